// Round 1
// baseline (723.395 us; speedup 1.0000x reference)
//
#include <hip/hip_runtime.h>

#define NN 2048
#define KK 8
#define DD 32
#define TN 16
#define TM 32
#define NC 4
#define CHUNK (NN / NC)      // 512
#define MTILES (CHUNK / TM)  // 16

__device__ __forceinline__ void softmax8(const float* s, int valid, float* p) {
  float mx = s[0];
#pragma unroll
  for (int k = 1; k < KK; ++k) mx = fmaxf(mx, s[k]);
  float e[KK];
  float sum = 0.0f;
#pragma unroll
  for (int k = 0; k < KK; ++k) { e[k] = __expf(s[k] - mx); sum += e[k]; }
  float r = valid ? (1.0f / sum) : 0.0f;
#pragma unroll
  for (int k = 0; k < KK; ++k) p[k] = e[k] * r;
}

// ---------------- projection + l2norm -> Z0 [K][N][D] ----------------
__global__ __launch_bounds__(256) void proj_kernel(const float* __restrict__ feat,
                                                   const float* __restrict__ W,
                                                   const float* __restrict__ bias,
                                                   float* __restrict__ Z) {
  __shared__ float f[128];
  const int n = blockIdx.x;
  const int t = threadIdx.x;
  if (t < 128) f[t] = feat[n * 128 + t];
  __syncthreads();
  const int k = t >> 5, c = t & 31;
  float s = bias[k * DD + c];
  const float* w = W + (k * 128) * DD + c;
#pragma unroll 16
  for (int d = 0; d < 128; ++d) s = fmaf(f[d], w[d * DD], s);
  float sq = s * s;
#pragma unroll
  for (int off = 16; off > 0; off >>= 1) sq += __shfl_xor(sq, off, 32);
  Z[(k * NN + n) * DD + c] = s / fmaxf(sqrtf(sq), 1e-12f);
}

// ---------------- fused att+softmax(k)+aggregate partial ----------------
// grid: (N/TN, NC); block 256.  partial[chunk][k][n][c]
__global__ __launch_bounds__(256, 2) void iter_partial(const float* __restrict__ Z,
                                                       const int* __restrict__ adj,
                                                       float* __restrict__ part) {
  // LDS: 16KB + 32KB + 16KB = 64KB, XOR-swizzled float4 chunks
  __shared__ float4 Zn4[KK][TN][8];
  __shared__ float4 Zm4[KK][TM][8];
  __shared__ float4 P4[KK][TN][8];

  const int t = threadIdx.x;
  const int n0 = blockIdx.x * TN;
  const int m0base = blockIdx.y * CHUNK;

  // stage Zn (once per block): 1024 float4, 4/thread
#pragma unroll
  for (int j = 0; j < 4; ++j) {
    int i = t + 256 * j;
    int row = i >> 3, q = i & 7;
    int k = row >> 4, nl = row & 15;
    float4 v = *(const float4*)&Z[(k * NN + n0 + nl) * DD + 4 * q];
    Zn4[k][nl][q ^ (nl & 7)] = v;
  }

  // phase-1 mapping: pair (nl, ml) and (nl, ml+16)
  const int p1_nl = t >> 4;  // 0..15
  const int p1_ml = t & 15;  // 0..15
  // phase-2 mapping: (k, nl2 & nl2+8, c in [8cq,8cq+8))
  const int p2_k = t >> 5;
  const int p2_nl2 = (t >> 2) & 7;
  const int p2_cq = t & 3;

  float acc[2][8];
#pragma unroll
  for (int h = 0; h < 2; ++h)
#pragma unroll
    for (int x = 0; x < 8; ++x) acc[h][x] = 0.0f;

  __syncthreads();

  for (int mt = 0; mt < MTILES; ++mt) {
    const int m0 = m0base + mt * TM;

    // prefetch Zm tile into registers (overlaps with prev phase-2 via 2 blocks/CU)
    float4 ld[8];
#pragma unroll
    for (int j = 0; j < 8; ++j) {
      int i = t + 256 * j;
      int row = i >> 3, q = i & 7;
      int k = row >> 5, ml = row & 31;
      ld[j] = *(const float4*)&Z[(k * NN + m0 + ml) * DD + 4 * q];
    }
    const int mk0 = adj[(n0 + p1_nl) * NN + m0 + p1_ml];
    const int mk1 = adj[(n0 + p1_nl) * NN + m0 + p1_ml + 16];

    __syncthreads();  // prev phase-2 done with Zm/P
#pragma unroll
    for (int j = 0; j < 8; ++j) {
      int i = t + 256 * j;
      int row = i >> 3, q = i & 7;
      int k = row >> 5, ml = row & 31;
      Zm4[k][ml][q ^ (ml & 7)] = ld[j];
    }
    __syncthreads();

    // ---- phase 1: dots for 2 pairs, all 8 channels ----
    float s0[KK], s1[KK];
#pragma unroll
    for (int k = 0; k < KK; ++k) {
      float a0 = 0.0f, a1 = 0.0f;
#pragma unroll
      for (int c4 = 0; c4 < 8; ++c4) {
        float4 zn = Zn4[k][p1_nl][c4 ^ (p1_nl & 7)];
        float4 za = Zm4[k][p1_ml][c4 ^ (p1_ml & 7)];
        float4 zb = Zm4[k][p1_ml + 16][c4 ^ (p1_ml & 7)];  // (ml+16)&7 == ml&7
        a0 = fmaf(zn.x, za.x, a0); a0 = fmaf(zn.y, za.y, a0);
        a0 = fmaf(zn.z, za.z, a0); a0 = fmaf(zn.w, za.w, a0);
        a1 = fmaf(zn.x, zb.x, a1); a1 = fmaf(zn.y, zb.y, a1);
        a1 = fmaf(zn.z, zb.z, a1); a1 = fmaf(zn.w, zb.w, a1);
      }
      s0[k] = a0; s1[k] = a1;
    }
    float p0[KK], p1v[KK];
    softmax8(s0, mk0 > 0, p0);
    softmax8(s1, mk1 > 0, p1v);
#pragma unroll
    for (int k = 0; k < KK; ++k) {
      float* Prow = (float*)&P4[k][p1_nl][0];
      const int swz = (p1_nl & 7) << 2;
      Prow[p1_ml ^ swz] = p0[k];
      Prow[(p1_ml + 16) ^ swz] = p1v[k];
    }
    __syncthreads();

    // ---- phase 2: acc[k, nl2/nl2+8, 8c] += P * Zm ----
#pragma unroll
    for (int mq = 0; mq < 8; ++mq) {
      float4 pa = P4[p2_k][p2_nl2][mq ^ (p2_nl2 & 7)];
      float4 pb = P4[p2_k][p2_nl2 + 8][mq ^ (p2_nl2 & 7)];
      float pav[4] = {pa.x, pa.y, pa.z, pa.w};
      float pbv[4] = {pb.x, pb.y, pb.z, pb.w};
#pragma unroll
      for (int j = 0; j < 4; ++j) {
        int m = 4 * mq + j;
        float4 z0 = Zm4[p2_k][m][(2 * p2_cq) ^ (m & 7)];
        float4 z1 = Zm4[p2_k][m][(2 * p2_cq + 1) ^ (m & 7)];
        float fa = pav[j], fb = pbv[j];
        acc[0][0] = fmaf(fa, z0.x, acc[0][0]); acc[0][1] = fmaf(fa, z0.y, acc[0][1]);
        acc[0][2] = fmaf(fa, z0.z, acc[0][2]); acc[0][3] = fmaf(fa, z0.w, acc[0][3]);
        acc[0][4] = fmaf(fa, z1.x, acc[0][4]); acc[0][5] = fmaf(fa, z1.y, acc[0][5]);
        acc[0][6] = fmaf(fa, z1.z, acc[0][6]); acc[0][7] = fmaf(fa, z1.w, acc[0][7]);
        acc[1][0] = fmaf(fb, z0.x, acc[1][0]); acc[1][1] = fmaf(fb, z0.y, acc[1][1]);
        acc[1][2] = fmaf(fb, z0.z, acc[1][2]); acc[1][3] = fmaf(fb, z0.w, acc[1][3]);
        acc[1][4] = fmaf(fb, z1.x, acc[1][4]); acc[1][5] = fmaf(fb, z1.y, acc[1][5]);
        acc[1][6] = fmaf(fb, z1.z, acc[1][6]); acc[1][7] = fmaf(fb, z1.w, acc[1][7]);
      }
    }
  }

  // write partials
  float* dst = part + (size_t)blockIdx.y * (KK * NN * DD);
#pragma unroll
  for (int h = 0; h < 2; ++h) {
    int nl = p2_nl2 + 8 * h;
    float* d = dst + (p2_k * NN + n0 + nl) * DD + 8 * p2_cq;
    *(float4*)&d[0] = make_float4(acc[h][0], acc[h][1], acc[h][2], acc[h][3]);
    *(float4*)&d[4] = make_float4(acc[h][4], acc[h][5], acc[h][6], acc[h][7]);
  }
}

// ---------------- residual + reduce partials + l2norm ----------------
__global__ __launch_bounds__(256) void reduce_norm(const float* __restrict__ Zin,
                                                   const float* __restrict__ part,
                                                   float* __restrict__ Zout) {
  const int n = blockIdx.x, t = threadIdx.x;
  const int k = t >> 5, c = t & 31;
  const int idx = (k * NN + n) * DD + c;
  float v = Zin[idx];
#pragma unroll
  for (int j = 0; j < NC; ++j) v += part[j * (KK * NN * DD) + idx];
  float sq = v * v;
#pragma unroll
  for (int off = 16; off > 0; off >>= 1) sq += __shfl_xor(sq, off, 32);
  Zout[idx] = v / fmaxf(sqrtf(sq), 1e-12f);
}

// ---------------- [K][N][D] -> [N][K*D] ----------------
__global__ __launch_bounds__(256) void out_kernel(const float* __restrict__ Zin,
                                                  float* __restrict__ out) {
  const int n = blockIdx.x, t = threadIdx.x;
  const int k = t >> 5, c = t & 31;
  out[n * (KK * DD) + t] = Zin[(k * NN + n) * DD + c];
}

extern "C" void kernel_launch(void* const* d_in, const int* in_sizes, int n_in,
                              void* d_out, int out_size, void* d_ws, size_t ws_size,
                              hipStream_t stream) {
  const int* adj = (const int*)d_in[0];
  const float* feat = (const float*)d_in[1];
  const float* W = (const float*)d_in[2];
  const float* b = (const float*)d_in[3];
  float* out = (float*)d_out;

  float* Z0 = (float*)d_ws;
  float* Z1 = Z0 + (size_t)KK * NN * DD;
  float* part = Z1 + (size_t)KK * NN * DD;  // NC * K*N*D floats

  proj_kernel<<<NN, 256, 0, stream>>>(feat, W, b, Z0);

  float* zi = Z0;
  float* zo = Z1;
  for (int it = 0; it < 4; ++it) {
    iter_partial<<<dim3(NN / TN, NC), 256, 0, stream>>>(zi, adj, part);
    reduce_norm<<<NN, 256, 0, stream>>>(zi, part, zo);
    float* tmp = zi; zi = zo; zo = tmp;
  }
  out_kernel<<<NN, 256, 0, stream>>>(zi, out);
}

// Round 2
// 313.984 us; speedup vs baseline: 2.3039x; 2.3039x over previous
//
#include <hip/hip_runtime.h>

#define NN 2048
#define KK 8
#define DD 32
#define ZSZ (KK * NN * DD)  // 524288 elements

typedef __attribute__((ext_vector_type(8))) short short8;
typedef __attribute__((ext_vector_type(4))) float f32x4;
typedef __attribute__((ext_vector_type(4))) unsigned int u32x4;

union U8 { unsigned int u[4]; short8 v; };

#define SELHI 0x07060302u
#define SELLO 0x05040100u

__device__ __forceinline__ unsigned int prm(unsigned int hiw, unsigned int low, unsigned int sel) {
  return __builtin_amdgcn_perm(hiw, low, sel);
}
// round-to-nearest-even fp32 -> bf16 (top 16 bits)
__device__ __forceinline__ unsigned int bfr(float x) {
  unsigned int u = __float_as_uint(x);
  return (u + 0x7fffu + ((u >> 16) & 1u)) >> 16;
}
// pack z as (hi|lo) residual split
__device__ __forceinline__ unsigned int packz(float x) {
  unsigned int h = bfr(x);
  float hf = __uint_as_float(h << 16);
  unsigned int l = bfr(x - hf);
  return (h << 16) | l;
}
__device__ __forceinline__ unsigned int packp(float a, float b) {  // a->lo16, b->hi16
  return (bfr(b) << 16) | bfr(a);
}
__device__ __forceinline__ f32x4 MF(short8 a, short8 b, f32x4 c) {
  return __builtin_amdgcn_mfma_f32_16x16x32_bf16(a, b, c, 0, 0, 0);
}
__device__ __forceinline__ void unpack8(u32x4 a, u32x4 b, U8& hi, U8& lo) {
  hi.u[0] = prm(a.y, a.x, SELHI); hi.u[1] = prm(a.w, a.z, SELHI);
  hi.u[2] = prm(b.y, b.x, SELHI); hi.u[3] = prm(b.w, b.z, SELHI);
  lo.u[0] = prm(a.y, a.x, SELLO); lo.u[1] = prm(a.w, a.z, SELLO);
  lo.u[2] = prm(b.y, b.x, SELLO); lo.u[3] = prm(b.w, b.z, SELLO);
}

// ---------------- projection + l2norm -> Z0 [K][N][D] fp32 ----------------
__global__ __launch_bounds__(256) void proj_kernel(const float* __restrict__ feat,
                                                   const float* __restrict__ W,
                                                   const float* __restrict__ bias,
                                                   float* __restrict__ Z) {
  __shared__ float f[128];
  const int n = blockIdx.x;
  const int t = threadIdx.x;
  if (t < 128) f[t] = feat[n * 128 + t];
  __syncthreads();
  const int k = t >> 5, c = t & 31;
  float s = bias[k * DD + c];
  const float* w = W + (k * 128) * DD + c;
#pragma unroll 16
  for (int d = 0; d < 128; ++d) s = fmaf(f[d], w[d * DD], s);
  float sq = s * s;
#pragma unroll
  for (int off = 16; off > 0; off >>= 1) sq += __shfl_xor(sq, off, 32);
  Z[(k * NN + n) * DD + c] = s / fmaxf(sqrtf(sq), 1e-12f);
}

// ---------------- adj -> bitmask [N][64 words] ----------------
__global__ __launch_bounds__(256) void maskpack_kernel(const int* __restrict__ adj,
                                                       unsigned int* __restrict__ mbits) {
  const int t = threadIdx.x;
  const int gid = blockIdx.x * 4 + (t >> 6);
  const int lane = t & 63;
  for (int it = 0; it < 64; ++it) {
    int idx = gid * 4096 + it * 64 + lane;
    int v = adj[idx];
    unsigned long long b = __ballot(v > 0);
    if (lane == 0) mbits[idx >> 5] = (unsigned int)b;
    if (lane == 32) mbits[idx >> 5] = (unsigned int)(b >> 32);
  }
}

// ---------------- Z fp32 -> Zpk [k][m][c] (hi|lo u32), Zt [k][c][m] ----------------
__global__ __launch_bounds__(256) void pack_kernel(const float* __restrict__ Z,
                                                   unsigned int* __restrict__ Zpk,
                                                   unsigned int* __restrict__ Zt) {
  __shared__ unsigned int T[32][33];
  const int t = threadIdx.x;
  const int k = blockIdx.x >> 6, mt = blockIdx.x & 63;
  const int m0 = mt * 32;
  {
    const int mloc = t >> 3, c4 = t & 7;
    const float* src = Z + ((size_t)(k * NN + m0 + mloc) * DD + 4 * c4);
    float4 v = *(const float4*)src;
    unsigned int u0 = packz(v.x), u1 = packz(v.y), u2 = packz(v.z), u3 = packz(v.w);
    u32x4 o = {u0, u1, u2, u3};
    *(u32x4*)&Zpk[(size_t)(k * NN + m0 + mloc) * DD + 4 * c4] = o;
    T[4 * c4 + 0][mloc] = u0;
    T[4 * c4 + 1][mloc] = u1;
    T[4 * c4 + 2][mloc] = u2;
    T[4 * c4 + 3][mloc] = u3;
  }
  __syncthreads();
  {
    const int cloc = t >> 3, m4 = t & 7;
    u32x4 o = {T[cloc][4 * m4 + 0], T[cloc][4 * m4 + 1], T[cloc][4 * m4 + 2], T[cloc][4 * m4 + 3]};
    *(u32x4*)&Zt[(size_t)k * (DD * NN) + (size_t)cloc * NN + m0 + 4 * m4] = o;
  }
}

// ---------------- fused MFMA iteration: gram + softmax(k) + aggregate ----------------
// grid (32 n-blocks, NC chunks), block 256 (4 waves, each wave owns 16 n-rows)
// LDS: ZMC [8][32][32]u32 (slot^m), ZMT [8][32][32]u32 (slot^c); P aliases ZMC (per-wave 512 u32)
__global__ __launch_bounds__(256, 2) void iter_kernel(const unsigned int* __restrict__ Zpk,
                                                      const unsigned int* __restrict__ Zt,
                                                      const unsigned int* __restrict__ mbits,
                                                      float* __restrict__ part, int nsteps) {
  __shared__ __align__(16) unsigned int lds[16384];
  const int t = threadIdx.x;
  const int w = t >> 6;
  const int lane = t & 63;
  const int l15 = lane & 15;
  const int g = lane >> 4;
  const int n0 = blockIdx.x * 64;
  const int nw = n0 + w * 16;
  const int mchunk = blockIdx.y * (nsteps * 32);

  // persistent Zn A-frags (hi/lo), from Zpk
  U8 ahi[KK], alo[KK];
#pragma unroll
  for (int k = 0; k < KK; ++k) {
    const unsigned int* p = Zpk + ((size_t)(k * NN + nw + l15) * DD + 8 * g);
    u32x4 a = *(const u32x4*)p;
    u32x4 b = *(const u32x4*)(p + 4);
    unpack8(a, b, ahi[k], alo[k]);
  }

  f32x4 O[KK][2];
#pragma unroll
  for (int k = 0; k < KK; ++k)
#pragma unroll
    for (int ch = 0; ch < 2; ++ch) O[k][ch] = {0.0f, 0.0f, 0.0f, 0.0f};

  const int sk = t >> 5;      // staging k (0..7)
  const int s31 = t & 31;
  const int sq_ = t & 7;      // staging quad

  for (int st = 0; st < nsteps; ++st) {
    const int mb = mchunk + st * 32;
    __syncthreads();
    // ---- stage Zmc [k][m][c-quads swizzled] and Zmt [k][c][m-quads swizzled] ----
#pragma unroll
    for (int j = 0; j < 8; ++j) {
      u32x4 v = *(const u32x4*)(Zpk + (size_t)sk * (NN * DD) + (size_t)mb * DD + 4 * s31 + 128 * j);
      int m = (s31 >> 3) + 4 * j;
      *(u32x4*)&lds[(sk * 32 + m) * 32 + 4 * (sq_ ^ (m & 7))] = v;
    }
#pragma unroll
    for (int j = 0; j < 8; ++j) {
      int c = (s31 >> 3) + 4 * j;
      u32x4 v = *(const u32x4*)(Zt + (size_t)sk * (DD * NN) + (size_t)c * NN + mb + 4 * sq_);
      *(u32x4*)&lds[8192 + (sk * 32 + c) * 32 + 4 * (sq_ ^ (c & 7))] = v;
    }
    __syncthreads();

    // ---- gram: S[k][sub] = Zn . Zm^T (hi/lo split) ----
    f32x4 S[KK][2];
#pragma unroll
    for (int k = 0; k < KK; ++k) {
#pragma unroll
      for (int sub = 0; sub < 2; ++sub) {
        int m = 16 * sub + l15;
        const unsigned int* row = &lds[(k * 32 + m) * 32];
        u32x4 b0 = *(const u32x4*)&row[4 * ((2 * g) ^ (m & 7))];
        u32x4 b1 = *(const u32x4*)&row[4 * ((2 * g + 1) ^ (m & 7))];
        U8 bhi, blo;
        unpack8(b0, b1, bhi, blo);
        f32x4 s = {0.0f, 0.0f, 0.0f, 0.0f};
        s = MF(ahi[k].v, bhi.v, s);
        s = MF(ahi[k].v, blo.v, s);
        s = MF(alo[k].v, bhi.v, s);
        S[k][sub] = s;
      }
    }

    // ---- softmax across k, in-register; S becomes P ----
    unsigned int mw[4];
#pragma unroll
    for (int r = 0; r < 4; ++r) mw[r] = mbits[(size_t)(nw + 4 * g + r) * 64 + (mb >> 5)];
#pragma unroll
    for (int sub = 0; sub < 2; ++sub) {
#pragma unroll
      for (int r = 0; r < 4; ++r) {
        float e[KK];
        float sum = 0.0f;
#pragma unroll
        for (int k = 0; k < KK; ++k) { e[k] = __expf(S[k][sub][r]); sum += e[k]; }
        int mlocal = 16 * sub + l15;
        float f = ((mw[r] >> mlocal) & 1u) ? (1.0f / sum) : 0.0f;
#pragma unroll
        for (int k = 0; k < KK; ++k) S[k][sub][r] = e[k] * f;
      }
    }

    __syncthreads();  // all waves done reading ZMC -> P may alias it

    // ---- per k-pair: P -> LDS (C->A transpose) -> aggregate MFMA ----
    unsigned int* Pw = &lds[w * 512];
#pragma unroll
    for (int kp = 0; kp < 4; ++kp) {
#pragma unroll
      for (int sub = 0; sub < 2; ++sub) {
#pragma unroll
        for (int r = 0; r < 4; ++r) {
          int n = 4 * g + r, m = 16 * sub + l15;
          int q = m >> 2;
          Pw[n * 32 + 4 * (q ^ (n & 7)) + (m & 3)] = packp(S[2 * kp][sub][r], S[2 * kp + 1][sub][r]);
        }
      }
      u32x4 a0 = *(const u32x4*)&Pw[l15 * 32 + 4 * ((2 * g) ^ (l15 & 7))];
      u32x4 a1 = *(const u32x4*)&Pw[l15 * 32 + 4 * ((2 * g + 1) ^ (l15 & 7))];
      U8 pk0, pk1;
      pk0.u[0] = prm(a0.y, a0.x, SELLO); pk0.u[1] = prm(a0.w, a0.z, SELLO);
      pk0.u[2] = prm(a1.y, a1.x, SELLO); pk0.u[3] = prm(a1.w, a1.z, SELLO);
      pk1.u[0] = prm(a0.y, a0.x, SELHI); pk1.u[1] = prm(a0.w, a0.z, SELHI);
      pk1.u[2] = prm(a1.y, a1.x, SELHI); pk1.u[3] = prm(a1.w, a1.z, SELHI);
#pragma unroll
      for (int kk = 0; kk < 2; ++kk) {
        int k = 2 * kp + kk;
#pragma unroll
        for (int ch = 0; ch < 2; ++ch) {
          int c = 16 * ch + l15;
          const unsigned int* row = &lds[8192 + (k * 32 + c) * 32];
          u32x4 b0 = *(const u32x4*)&row[4 * ((2 * g) ^ (c & 7))];
          u32x4 b1 = *(const u32x4*)&row[4 * ((2 * g + 1) ^ (c & 7))];
          U8 bhi, blo;
          unpack8(b0, b1, bhi, blo);
          O[k][ch] = MF(kk ? pk1.v : pk0.v, bhi.v, O[k][ch]);
          O[k][ch] = MF(kk ? pk1.v : pk0.v, blo.v, O[k][ch]);
        }
      }
    }
  }

  // ---- write partials: part[chunk][k][n][c] ----
  float* dst = part + (size_t)blockIdx.y * ZSZ;
#pragma unroll
  for (int k = 0; k < KK; ++k)
#pragma unroll
    for (int ch = 0; ch < 2; ++ch) {
      f32x4 o = O[k][ch];
#pragma unroll
      for (int r = 0; r < 4; ++r)
        dst[(size_t)(k * NN + nw + 4 * g + r) * DD + 16 * ch + l15] = o[r];
    }
}

// ---------------- residual + reduce partials + l2norm ----------------
__global__ __launch_bounds__(256) void reduce_norm(const float* __restrict__ Zin,
                                                   const float* __restrict__ part,
                                                   float* __restrict__ Zout, int nc) {
  const int n = blockIdx.x, t = threadIdx.x;
  const int k = t >> 5, c = t & 31;
  const int idx = (k * NN + n) * DD + c;
  float v = Zin[idx];
  for (int j = 0; j < nc; ++j) v += part[(size_t)j * ZSZ + idx];
  float sq = v * v;
#pragma unroll
  for (int off = 16; off > 0; off >>= 1) sq += __shfl_xor(sq, off, 32);
  Zout[idx] = v / fmaxf(sqrtf(sq), 1e-12f);
}

// ---------------- [K][N][D] -> [N][K*D] ----------------
__global__ __launch_bounds__(256) void out_kernel(const float* __restrict__ Zin,
                                                  float* __restrict__ out) {
  const int n = blockIdx.x, t = threadIdx.x;
  const int k = t >> 5, c = t & 31;
  out[n * (KK * DD) + t] = Zin[(k * NN + n) * DD + c];
}

extern "C" void kernel_launch(void* const* d_in, const int* in_sizes, int n_in,
                              void* d_out, int out_size, void* d_ws, size_t ws_size,
                              hipStream_t stream) {
  const int* adj = (const int*)d_in[0];
  const float* feat = (const float*)d_in[1];
  const float* W = (const float*)d_in[2];
  const float* b = (const float*)d_in[3];
  float* out = (float*)d_out;

  // pick NC (chunks) to fit workspace
  int NC = 16;
  while (NC > 1) {
    size_t need = ((size_t)ZSZ * (4 + NC) + NN * 64) * 4;
    if (need <= ws_size) break;
    NC >>= 1;
  }
  const int nsteps = NN / NC / 32;

  float* Z0 = (float*)d_ws;
  float* Z1 = Z0 + ZSZ;
  unsigned int* Zpk = (unsigned int*)(Z1 + ZSZ);
  unsigned int* Zt = Zpk + ZSZ;
  unsigned int* mbits = Zt + ZSZ;
  float* part = (float*)(mbits + NN * 64);

  maskpack_kernel<<<256, 256, 0, stream>>>(adj, mbits);
  proj_kernel<<<NN, 256, 0, stream>>>(feat, W, b, Z0);

  float* zi = Z0;
  float* zo = Z1;
  for (int it = 0; it < 4; ++it) {
    pack_kernel<<<512, 256, 0, stream>>>(zi, Zpk, Zt);
    iter_kernel<<<dim3(32, NC), 256, 0, stream>>>(Zpk, Zt, mbits, part, nsteps);
    reduce_norm<<<NN, 256, 0, stream>>>(zi, part, zo, NC);
    float* tmp = zi; zi = zo; zo = tmp;
  }
  out_kernel<<<NN, 256, 0, stream>>>(zi, out);
}

// Round 3
// 237.369 us; speedup vs baseline: 3.0476x; 1.3228x over previous
//
#include <hip/hip_runtime.h>

#define NN 2048
#define KK 8
#define DD 32
#define ZSZ (KK * NN * DD)  // 524288

typedef __attribute__((ext_vector_type(8))) short short8;
typedef __attribute__((ext_vector_type(4))) float f32x4;
typedef __attribute__((ext_vector_type(4))) unsigned int u32x4;

union UU { u32x4 q; short8 v; unsigned int u[4]; };

#define SELHI 0x07060302u
#define SELLO 0x05040100u

__device__ __forceinline__ unsigned int prm(unsigned int a, unsigned int b, unsigned int sel) {
  return __builtin_amdgcn_perm(a, b, sel);
}
// round-to-nearest-even fp32 -> bf16
__device__ __forceinline__ unsigned int bfr(float x) {
  unsigned int u = __float_as_uint(x);
  return (u + 0x7fffu + ((u >> 16) & 1u)) >> 16;
}
__device__ __forceinline__ unsigned int packp(float a, float b) {  // a->lo16, b->hi16
  return (bfr(b) << 16) | bfr(a);
}
__device__ __forceinline__ f32x4 MF(short8 a, short8 b, f32x4 c) {
  return __builtin_amdgcn_mfma_f32_16x16x32_bf16(a, b, c, 0, 0, 0);
}
__device__ __forceinline__ short8 as_s8(u32x4 x) { UU u; u.q = x; return u.v; }
__device__ __forceinline__ int swz(int m) { return (m ^ (m >> 2)) & 3; }

// ---------------- projection + l2norm -> Z0 [K][N][D] fp32 ----------------
__global__ __launch_bounds__(256) void proj_kernel(const float* __restrict__ feat,
                                                   const float* __restrict__ W,
                                                   const float* __restrict__ bias,
                                                   float* __restrict__ Z) {
  __shared__ float f[128];
  const int n = blockIdx.x;
  const int t = threadIdx.x;
  if (t < 128) f[t] = feat[n * 128 + t];
  __syncthreads();
  const int k = t >> 5, c = t & 31;
  float s = bias[k * DD + c];
  const float* w = W + (k * 128) * DD + c;
#pragma unroll 16
  for (int d = 0; d < 128; ++d) s = fmaf(f[d], w[d * DD], s);
  float sq = s * s;
#pragma unroll
  for (int off = 16; off > 0; off >>= 1) sq += __shfl_xor(sq, off, 32);
  Z[(k * NN + n) * DD + c] = s / fmaxf(sqrtf(sq), 1e-12f);
}

// ---------------- adj -> bitmask [N][64 words] ----------------
__global__ __launch_bounds__(256) void maskpack_kernel(const int* __restrict__ adj,
                                                       unsigned int* __restrict__ mbits) {
  const int t = threadIdx.x;
  const int gid = blockIdx.x * 4 + (t >> 6);
  const int lane = t & 63;
  for (int it = 0; it < 64; ++it) {
    int idx = gid * 4096 + it * 64 + lane;
    int v = adj[idx];
    unsigned long long b = __ballot(v > 0);
    if (lane == 0) mbits[idx >> 5] = (unsigned int)b;
    if (lane == 32) mbits[idx >> 5] = (unsigned int)(b >> 32);
  }
}

// ------- fused: Z = l2norm(Zin + sum partials); write Z fp32 + bf16 planes -------
// grid (8k * 64 mtiles), block 256.  nc==0: pack-only (Zin already normalized).
__global__ __launch_bounds__(256) void rp_kernel(const float* __restrict__ Zin,
                                                 const float* __restrict__ part, int nc,
                                                 float* __restrict__ Zout,
                                                 unsigned short* __restrict__ Zghi,
                                                 unsigned short* __restrict__ Zglo,
                                                 unsigned short* __restrict__ Zthi) {
  __shared__ unsigned short T[DD][33];
  const int t = threadIdx.x;
  const int k = blockIdx.x >> 6, mt = blockIdx.x & 63;
  const int m0 = mt * 32;
  const int mloc = t >> 3, c4 = t & 7;
  const size_t idx = (size_t)(k * NN + m0 + mloc) * DD + 4 * c4;
  float4 v = *(const float4*)&Zin[idx];
  for (int j = 0; j < nc; ++j) {
    float4 p = *(const float4*)&part[(size_t)j * ZSZ + idx];
    v.x += p.x; v.y += p.y; v.z += p.z; v.w += p.w;
  }
  float sq = v.x * v.x + v.y * v.y + v.z * v.z + v.w * v.w;
  sq += __shfl_xor(sq, 1, 8);
  sq += __shfl_xor(sq, 2, 8);
  sq += __shfl_xor(sq, 4, 8);
  const float sc = 1.0f / fmaxf(sqrtf(sq), 1e-12f);
  float z[4] = {v.x * sc, v.y * sc, v.z * sc, v.w * sc};
  if (nc) *(float4*)&Zout[idx] = make_float4(z[0], z[1], z[2], z[3]);
  unsigned int hi[4], lo[4];
#pragma unroll
  for (int e = 0; e < 4; ++e) {
    hi[e] = bfr(z[e]);
    lo[e] = bfr(z[e] - __uint_as_float(hi[e] << 16));
    T[4 * c4 + e][mloc] = (unsigned short)hi[e];
  }
  *(uint2*)&Zghi[idx] = make_uint2(hi[0] | (hi[1] << 16), hi[2] | (hi[3] << 16));
  *(uint2*)&Zglo[idx] = make_uint2(lo[0] | (lo[1] << 16), lo[2] | (lo[3] << 16));
  __syncthreads();
  const int cloc = t >> 3, m4 = t & 7;
  unsigned int o0 = (unsigned int)T[cloc][4 * m4 + 0] | ((unsigned int)T[cloc][4 * m4 + 1] << 16);
  unsigned int o1 = (unsigned int)T[cloc][4 * m4 + 2] | ((unsigned int)T[cloc][4 * m4 + 3] << 16);
  *(uint2*)&Zthi[(size_t)k * DD * NN + (size_t)cloc * NN + m0 + 4 * m4] = make_uint2(o0, o1);
}

// ---------------- fused MFMA iteration: gram + softmax(k) + aggregate ----------------
// grid (32 n-blocks, NC chunks), block 256 (4 waves x 16 n-rows)
// LDS u32: [0,4096) zghi tile, [4096,8192) zglo, [8192,12288) zthi, [12288,14336) per-wave P
__global__ __launch_bounds__(256, 2) void iter_kernel(const unsigned short* __restrict__ Zghi,
                                                      const unsigned short* __restrict__ Zglo,
                                                      const unsigned short* __restrict__ Zthi,
                                                      const unsigned int* __restrict__ mbits,
                                                      float* __restrict__ part, int nsteps) {
  __shared__ __align__(16) unsigned int lds[14336];
  const int t = threadIdx.x;
  const int w = t >> 6;
  const int lane = t & 63;
  const int l15 = lane & 15;
  const int g = lane >> 4;
  const int nw = blockIdx.x * 64 + w * 16;
  const int mchunk = blockIdx.y * (nsteps * 32);

  const unsigned int* Zghi_u = (const unsigned int*)Zghi;
  const unsigned int* Zglo_u = (const unsigned int*)Zglo;
  const unsigned int* Zthi_u = (const unsigned int*)Zthi;

  // persistent A-frags (hi only): A[k] = Zn[n=l15][c=8g..8g+8)
  short8 A[KK];
#pragma unroll
  for (int k = 0; k < KK; ++k)
    A[k] = as_s8(*(const u32x4*)&Zghi_u[(size_t)(k * NN + nw + l15) * 16 + 4 * g]);

  f32x4 O[KK][2];
#pragma unroll
  for (int k = 0; k < KK; ++k)
#pragma unroll
    for (int ch = 0; ch < 2; ++ch) O[k][ch] = {0.0f, 0.0f, 0.0f, 0.0f};

  // staging mapping: quad q fixed per thread, rows r = 64j + (t>>2)
  const int sqd = t & 3;
  const int sr0 = t >> 2;

  u32x4 Lgh[4], Lgl[4], Lth[4];
  auto do_loads = [&](int mb) {
#pragma unroll
    for (int j = 0; j < 4; ++j) {
      int r = 64 * j + sr0;
      int k = r >> 5, rm = r & 31;
      Lgh[j] = *(const u32x4*)&Zghi_u[(size_t)k * (NN * 16) + (size_t)(mb + rm) * 16 + sqd * 4];
      Lgl[j] = *(const u32x4*)&Zglo_u[(size_t)k * (NN * 16) + (size_t)(mb + rm) * 16 + sqd * 4];
      Lth[j] = *(const u32x4*)&Zthi_u[(size_t)k * (NN * 16) + (size_t)rm * (NN / 2) + (mb >> 1) + sqd * 4];
    }
  };
  do_loads(mchunk);

  for (int st = 0; st < nsteps; ++st) {
    const int mb = mchunk + st * 32;
    __syncthreads();  // everyone done reading prev tiles
#pragma unroll
    for (int j = 0; j < 4; ++j) {
      int r = 64 * j + sr0;
      int k = r >> 5, rm = r & 31;
      int qs = (sqd ^ swz(rm)) << 2;
      *(u32x4*)&lds[(k * 32 + rm) * 16 + qs] = Lgh[j];
      *(u32x4*)&lds[4096 + (k * 32 + rm) * 16 + qs] = Lgl[j];
      *(u32x4*)&lds[8192 + (k * 32 + rm) * 16 + qs] = Lth[j];
    }
    __syncthreads();
    if (st + 1 < nsteps) do_loads(mb + 32);

    // ---- gram: S[n][m] = ahi . (bhi + blo) ----
    f32x4 S[KK][2];
#pragma unroll
    for (int k = 0; k < KK; ++k) {
#pragma unroll
      for (int sub = 0; sub < 2; ++sub) {
        int m = 16 * sub + l15;
        int base = (k * 32 + m) * 16 + ((g ^ swz(m)) << 2);
        u32x4 bh = *(const u32x4*)&lds[base];
        u32x4 bl = *(const u32x4*)&lds[4096 + base];
        f32x4 s = {0.0f, 0.0f, 0.0f, 0.0f};
        s = MF(A[k], as_s8(bh), s);
        s = MF(A[k], as_s8(bl), s);
        S[k][sub] = s;
      }
    }

    // ---- softmax across k (in-register) ----
    unsigned int mw[4];
#pragma unroll
    for (int r = 0; r < 4; ++r) mw[r] = mbits[(size_t)(nw + 4 * g + r) * 64 + (mb >> 5)];
#pragma unroll
    for (int sub = 0; sub < 2; ++sub) {
#pragma unroll
      for (int r = 0; r < 4; ++r) {
        float e[KK];
        float sum = 0.0f;
#pragma unroll
        for (int k = 0; k < KK; ++k) { e[k] = __expf(S[k][sub][r]); sum += e[k]; }
        int ml = 16 * sub + l15;
        float f = ((mw[r] >> ml) & 1u) ? (1.0f / sum) : 0.0f;
#pragma unroll
        for (int k = 0; k < KK; ++k) S[k][sub][r] = e[k] * f;
      }
    }

    // ---- per k-pair: P -> per-wave LDS (C->A transpose), aggregate hi-only ----
    unsigned int* Pw = &lds[12288 + w * 512];
#pragma unroll
    for (int kp = 0; kp < 4; ++kp) {
#pragma unroll
      for (int sub = 0; sub < 2; ++sub) {
#pragma unroll
        for (int r = 0; r < 4; ++r) {
          int n = 4 * g + r, m = 16 * sub + l15;
          int oct = (m >> 3) ^ (n & 3) ^ ((n >> 2) & 3);
          Pw[n * 32 + oct * 8 + (m & 7)] = packp(S[2 * kp][sub][r], S[2 * kp + 1][sub][r]);
        }
      }
      int rbase = l15 * 32 + ((g ^ (l15 & 3) ^ ((l15 >> 2) & 3)) << 3);
      u32x4 a0 = *(const u32x4*)&Pw[rbase];
      u32x4 a1 = *(const u32x4*)&Pw[rbase + 4];
      UU pk0, pk1;
      pk0.u[0] = prm(a0.y, a0.x, SELLO); pk0.u[1] = prm(a0.w, a0.z, SELLO);
      pk0.u[2] = prm(a1.y, a1.x, SELLO); pk0.u[3] = prm(a1.w, a1.z, SELLO);
      pk1.u[0] = prm(a0.y, a0.x, SELHI); pk1.u[1] = prm(a0.w, a0.z, SELHI);
      pk1.u[2] = prm(a1.y, a1.x, SELHI); pk1.u[3] = prm(a1.w, a1.z, SELHI);
#pragma unroll
      for (int kk = 0; kk < 2; ++kk) {
        int k = 2 * kp + kk;
#pragma unroll
        for (int ch = 0; ch < 2; ++ch) {
          int c = 16 * ch + l15;
          u32x4 b = *(const u32x4*)&lds[8192 + (k * 32 + c) * 16 + ((g ^ swz(c)) << 2)];
          O[k][ch] = MF(kk ? pk1.v : pk0.v, as_s8(b), O[k][ch]);
        }
      }
    }
  }

  // ---- write partials: part[chunk][k][n][c] ----
  float* dst = part + (size_t)blockIdx.y * ZSZ;
#pragma unroll
  for (int k = 0; k < KK; ++k)
#pragma unroll
    for (int ch = 0; ch < 2; ++ch) {
      f32x4 o = O[k][ch];
#pragma unroll
      for (int r = 0; r < 4; ++r)
        dst[(size_t)(k * NN + nw + 4 * g + r) * DD + 16 * ch + l15] = o[r];
    }
}

// ---------------- final: residual + reduce + l2norm + [N][K*D] output ----------------
__global__ __launch_bounds__(256) void ro_kernel(const float* __restrict__ Zin,
                                                 const float* __restrict__ part, int nc,
                                                 float* __restrict__ out) {
  const int n = blockIdx.x, t = threadIdx.x;
  const int k = t >> 5, c = t & 31;
  const size_t idx = (size_t)(k * NN + n) * DD + c;
  float v = Zin[idx];
  for (int j = 0; j < nc; ++j) v += part[(size_t)j * ZSZ + idx];
  float sq = v * v;
#pragma unroll
  for (int off = 16; off > 0; off >>= 1) sq += __shfl_xor(sq, off, 32);
  out[n * (KK * DD) + t] = v / fmaxf(sqrtf(sq), 1e-12f);
}

extern "C" void kernel_launch(void* const* d_in, const int* in_sizes, int n_in,
                              void* d_out, int out_size, void* d_ws, size_t ws_size,
                              hipStream_t stream) {
  const int* adj = (const int*)d_in[0];
  const float* feat = (const float*)d_in[1];
  const float* W = (const float*)d_in[2];
  const float* b = (const float*)d_in[3];
  float* out = (float*)d_out;

  int NC = 16;
  while (NC > 1) {
    size_t need = ((size_t)ZSZ * (2 + NC) + NN * 64) * 4 + (size_t)ZSZ * 3 * 2;
    if (need <= ws_size) break;
    NC >>= 1;
  }
  const int nsteps = NN / NC / 32;

  float* Z0 = (float*)d_ws;
  float* Z1 = Z0 + ZSZ;
  unsigned short* Zghi = (unsigned short*)(Z1 + ZSZ);
  unsigned short* Zglo = Zghi + ZSZ;
  unsigned short* Zthi = Zglo + ZSZ;
  unsigned int* mbits = (unsigned int*)(Zthi + ZSZ);
  float* part = (float*)(mbits + NN * 64);

  maskpack_kernel<<<256, 256, 0, stream>>>(adj, mbits);
  proj_kernel<<<NN, 256, 0, stream>>>(feat, W, b, Z0);

  // pack-only (Z0 already normalized)
  rp_kernel<<<512, 256, 0, stream>>>(Z0, part, 0, Z1, Zghi, Zglo, Zthi);

  float* zi = Z0;
  float* zo = Z1;
  for (int it = 0; it < 4; ++it) {
    iter_kernel<<<dim3(32, NC), 256, 0, stream>>>(Zghi, Zglo, Zthi, mbits, part, nsteps);
    if (it < 3) {
      rp_kernel<<<512, 256, 0, stream>>>(zi, part, NC, zo, Zghi, Zglo, Zthi);
      float* tmp = zi; zi = zo; zo = tmp;
    } else {
      ro_kernel<<<NN, 256, 0, stream>>>(zi, part, NC, out);
    }
  }
}

// Round 4
// 225.877 us; speedup vs baseline: 3.2026x; 1.0509x over previous
//
#include <hip/hip_runtime.h>

#define NN 2048
#define KK 8
#define DD 32
#define ZSZ (KK * NN * DD)  // 524288

typedef __attribute__((ext_vector_type(8))) short short8;
typedef __attribute__((ext_vector_type(4))) float f32x4;
typedef __attribute__((ext_vector_type(4))) unsigned int u32x4;

union UU { u32x4 q; short8 v; unsigned int u[4]; };

#define SELHI 0x07060302u
#define SELLO 0x05040100u
#define PSTR 36  // padded P row stride (u32) -> conflict-free b128 reads

__device__ __forceinline__ unsigned int prm(unsigned int a, unsigned int b, unsigned int sel) {
  return __builtin_amdgcn_perm(a, b, sel);
}
// round-to-nearest-even fp32 -> bf16
__device__ __forceinline__ unsigned int bfr(float x) {
  unsigned int u = __float_as_uint(x);
  return (u + 0x7fffu + ((u >> 16) & 1u)) >> 16;
}
__device__ __forceinline__ unsigned int packp(float a, float b) {  // a->lo16, b->hi16
  return (bfr(b) << 16) | bfr(a);
}
__device__ __forceinline__ f32x4 MF(short8 a, short8 b, f32x4 c) {
  return __builtin_amdgcn_mfma_f32_16x16x32_bf16(a, b, c, 0, 0, 0);
}
__device__ __forceinline__ short8 as_s8(u32x4 x) { UU u; u.q = x; return u.v; }
__device__ __forceinline__ int swz(int m) { return (m ^ (m >> 2)) & 3; }

// ---------------- projection + l2norm -> Z0 [K][N][D] fp32 ----------------
__global__ __launch_bounds__(256) void proj_kernel(const float* __restrict__ feat,
                                                   const float* __restrict__ W,
                                                   const float* __restrict__ bias,
                                                   float* __restrict__ Z) {
  __shared__ float f[128];
  const int n = blockIdx.x;
  const int t = threadIdx.x;
  if (t < 128) f[t] = feat[n * 128 + t];
  __syncthreads();
  const int k = t >> 5, c = t & 31;
  float s = bias[k * DD + c];
  const float* w = W + (k * 128) * DD + c;
#pragma unroll 16
  for (int d = 0; d < 128; ++d) s = fmaf(f[d], w[d * DD], s);
  float sq = s * s;
#pragma unroll
  for (int off = 16; off > 0; off >>= 1) sq += __shfl_xor(sq, off, 32);
  Z[(k * NN + n) * DD + c] = s / fmaxf(sqrtf(sq), 1e-12f);
}

// ---------------- adj -> bitmask [N][64 words] ----------------
__global__ __launch_bounds__(256) void maskpack_kernel(const int* __restrict__ adj,
                                                       unsigned int* __restrict__ mbits) {
  const int t = threadIdx.x;
  const int gid = blockIdx.x * 4 + (t >> 6);
  const int lane = t & 63;
  for (int it = 0; it < 64; ++it) {
    int idx = gid * 4096 + it * 64 + lane;
    int v = adj[idx];
    unsigned long long b = __ballot(v > 0);
    if (lane == 0) mbits[idx >> 5] = (unsigned int)b;
    if (lane == 32) mbits[idx >> 5] = (unsigned int)(b >> 32);
  }
}

// ------- fused: Z = l2norm(Zin + sum partials); write Z fp32 + hi plane + hi^T -------
// grid (8k * 64 mtiles), block 256.  nc==0: pack-only (Zin already normalized).
__global__ __launch_bounds__(256) void rp_kernel(const float* __restrict__ Zin,
                                                 const float* __restrict__ part, int nc,
                                                 float* __restrict__ Zout,
                                                 unsigned short* __restrict__ Zghi,
                                                 unsigned short* __restrict__ Zthi) {
  __shared__ unsigned short T[DD][33];
  const int t = threadIdx.x;
  const int k = blockIdx.x >> 6, mt = blockIdx.x & 63;
  const int m0 = mt * 32;
  const int mloc = t >> 3, c4 = t & 7;
  const size_t idx = (size_t)(k * NN + m0 + mloc) * DD + 4 * c4;
  float4 v = *(const float4*)&Zin[idx];
  for (int j = 0; j < nc; ++j) {
    float4 p = *(const float4*)&part[(size_t)j * ZSZ + idx];
    v.x += p.x; v.y += p.y; v.z += p.z; v.w += p.w;
  }
  float sq = v.x * v.x + v.y * v.y + v.z * v.z + v.w * v.w;
  sq += __shfl_xor(sq, 1, 8);
  sq += __shfl_xor(sq, 2, 8);
  sq += __shfl_xor(sq, 4, 8);
  const float sc = 1.0f / fmaxf(sqrtf(sq), 1e-12f);
  float z[4] = {v.x * sc, v.y * sc, v.z * sc, v.w * sc};
  if (nc) *(float4*)&Zout[idx] = make_float4(z[0], z[1], z[2], z[3]);
  unsigned int hi[4];
#pragma unroll
  for (int e = 0; e < 4; ++e) {
    hi[e] = bfr(z[e]);
    T[4 * c4 + e][mloc] = (unsigned short)hi[e];
  }
  *(uint2*)&Zghi[idx] = make_uint2(hi[0] | (hi[1] << 16), hi[2] | (hi[3] << 16));
  __syncthreads();
  const int cloc = t >> 3, m4 = t & 7;
  unsigned int o0 = (unsigned int)T[cloc][4 * m4 + 0] | ((unsigned int)T[cloc][4 * m4 + 1] << 16);
  unsigned int o1 = (unsigned int)T[cloc][4 * m4 + 2] | ((unsigned int)T[cloc][4 * m4 + 3] << 16);
  *(uint2*)&Zthi[(size_t)k * DD * NN + (size_t)cloc * NN + m0 + 4 * m4] = make_uint2(o0, o1);
}

// ---------------- fused MFMA iteration: gram + softmax(k) + aggregate ----------------
// grid (32 n-blocks, NC chunks), block 256 (4 waves x 16 n-rows)
// LDS u32: [0,4096) hi tile [k][m][c], [4096,8192) hi^T tile [k][c][m],
//          [8192,8192+4*PSTR*16) per-wave P (row stride PSTR)
__global__ __launch_bounds__(256, 2) void iter_kernel(const unsigned short* __restrict__ Zghi,
                                                      const unsigned short* __restrict__ Zthi,
                                                      const unsigned int* __restrict__ mbits,
                                                      float* __restrict__ part, int nsteps) {
  __shared__ __align__(16) unsigned int lds[8192 + 4 * PSTR * 16];
  const int t = threadIdx.x;
  const int w = t >> 6;
  const int lane = t & 63;
  const int l15 = lane & 15;
  const int g = lane >> 4;
  const int nw = blockIdx.x * 64 + w * 16;
  const int mchunk = blockIdx.y * (nsteps * 32);

  const unsigned int* Zghi_u = (const unsigned int*)Zghi;
  const unsigned int* Zthi_u = (const unsigned int*)Zthi;

  // persistent A-frags (hi plane): A[k] = Zn[n=l15][c=8g..8g+8)
  short8 A[KK];
#pragma unroll
  for (int k = 0; k < KK; ++k)
    A[k] = as_s8(*(const u32x4*)&Zghi_u[(size_t)(k * NN + nw + l15) * 16 + 4 * g]);

  f32x4 O[KK][2];
#pragma unroll
  for (int k = 0; k < KK; ++k)
#pragma unroll
    for (int ch = 0; ch < 2; ++ch) O[k][ch] = {0.0f, 0.0f, 0.0f, 0.0f};

  // staging mapping: quad q fixed per thread, rows r = 64j + (t>>2)
  const int sqd = t & 3;
  const int sr0 = t >> 2;

  u32x4 Lgh[4], Lth[4];
  auto do_loads = [&](int mb) {
#pragma unroll
    for (int j = 0; j < 4; ++j) {
      int r = 64 * j + sr0;
      int k = r >> 5, rm = r & 31;
      Lgh[j] = *(const u32x4*)&Zghi_u[(size_t)k * (NN * 16) + (size_t)(mb + rm) * 16 + sqd * 4];
      Lth[j] = *(const u32x4*)&Zthi_u[(size_t)k * (NN * 16) + (size_t)rm * (NN / 2) + (mb >> 1) + sqd * 4];
    }
  };
  do_loads(mchunk);

  for (int st = 0; st < nsteps; ++st) {
    const int mb = mchunk + st * 32;
    __syncthreads();  // everyone done reading prev tiles
#pragma unroll
    for (int j = 0; j < 4; ++j) {
      int r = 64 * j + sr0;
      int rm = r & 31;
      int qs = (sqd ^ swz(rm)) << 2;
      *(u32x4*)&lds[r * 16 + qs] = Lgh[j];
      *(u32x4*)&lds[4096 + r * 16 + qs] = Lth[j];
    }
    __syncthreads();
    if (st + 1 < nsteps) do_loads(mb + 32);

    // ---- gram: S[n][m] = ahi . bhi ----
    f32x4 S[KK][2];
#pragma unroll
    for (int k = 0; k < KK; ++k) {
#pragma unroll
      for (int sub = 0; sub < 2; ++sub) {
        int m = 16 * sub + l15;
        u32x4 bh = *(const u32x4*)&lds[(k * 32 + m) * 16 + ((g ^ swz(m)) << 2)];
        f32x4 s = {0.0f, 0.0f, 0.0f, 0.0f};
        s = MF(A[k], as_s8(bh), s);
        S[k][sub] = s;
      }
    }

    // ---- softmax across k (in-register) ----
    unsigned int mw[4];
#pragma unroll
    for (int r = 0; r < 4; ++r) mw[r] = mbits[(size_t)(nw + 4 * g + r) * 64 + (mb >> 5)];
#pragma unroll
    for (int sub = 0; sub < 2; ++sub) {
#pragma unroll
      for (int r = 0; r < 4; ++r) {
        float e[KK];
        float sum = 0.0f;
#pragma unroll
        for (int k = 0; k < KK; ++k) { e[k] = __expf(S[k][sub][r]); sum += e[k]; }
        int ml = 16 * sub + l15;
        float f = ((mw[r] >> ml) & 1u) ? __builtin_amdgcn_rcpf(sum) : 0.0f;
#pragma unroll
        for (int k = 0; k < KK; ++k) S[k][sub][r] = e[k] * f;
      }
    }

    // ---- per k-pair: P -> per-wave LDS (C->A transpose, stride-36 rows), aggregate ----
    unsigned int* Pw = &lds[8192 + w * (PSTR * 16)];
#pragma unroll
    for (int kp = 0; kp < 4; ++kp) {
#pragma unroll
      for (int sub = 0; sub < 2; ++sub) {
#pragma unroll
        for (int r = 0; r < 4; ++r) {
          int n = 4 * g + r, m = 16 * sub + l15;
          Pw[n * PSTR + m] = packp(S[2 * kp][sub][r], S[2 * kp + 1][sub][r]);
        }
      }
      u32x4 a0 = *(const u32x4*)&Pw[l15 * PSTR + 8 * g];
      u32x4 a1 = *(const u32x4*)&Pw[l15 * PSTR + 8 * g + 4];
      UU pk0, pk1;
      pk0.u[0] = prm(a0.y, a0.x, SELLO); pk0.u[1] = prm(a0.w, a0.z, SELLO);
      pk0.u[2] = prm(a1.y, a1.x, SELLO); pk0.u[3] = prm(a1.w, a1.z, SELLO);
      pk1.u[0] = prm(a0.y, a0.x, SELHI); pk1.u[1] = prm(a0.w, a0.z, SELHI);
      pk1.u[2] = prm(a1.y, a1.x, SELHI); pk1.u[3] = prm(a1.w, a1.z, SELHI);
#pragma unroll
      for (int kk = 0; kk < 2; ++kk) {
        int k = 2 * kp + kk;
#pragma unroll
        for (int ch = 0; ch < 2; ++ch) {
          int c = 16 * ch + l15;
          u32x4 b = *(const u32x4*)&lds[4096 + (k * 32 + c) * 16 + ((g ^ swz(c)) << 2)];
          O[k][ch] = MF(kk ? pk1.v : pk0.v, as_s8(b), O[k][ch]);
        }
      }
    }
  }

  // ---- write partials: part[chunk][k][n][c] ----
  float* dst = part + (size_t)blockIdx.y * ZSZ;
#pragma unroll
  for (int k = 0; k < KK; ++k)
#pragma unroll
    for (int ch = 0; ch < 2; ++ch) {
      f32x4 o = O[k][ch];
#pragma unroll
      for (int r = 0; r < 4; ++r)
        dst[(size_t)(k * NN + nw + 4 * g + r) * DD + 16 * ch + l15] = o[r];
    }
}

// ---------------- final: residual + reduce + l2norm + [N][K*D] output ----------------
__global__ __launch_bounds__(256) void ro_kernel(const float* __restrict__ Zin,
                                                 const float* __restrict__ part, int nc,
                                                 float* __restrict__ out) {
  const int n = blockIdx.x, t = threadIdx.x;
  const int k = t >> 5, c = t & 31;
  const size_t idx = (size_t)(k * NN + n) * DD + c;
  float v = Zin[idx];
  for (int j = 0; j < nc; ++j) v += part[(size_t)j * ZSZ + idx];
  float sq = v * v;
#pragma unroll
  for (int off = 16; off > 0; off >>= 1) sq += __shfl_xor(sq, off, 32);
  out[n * (KK * DD) + t] = v / fmaxf(sqrtf(sq), 1e-12f);
}

extern "C" void kernel_launch(void* const* d_in, const int* in_sizes, int n_in,
                              void* d_out, int out_size, void* d_ws, size_t ws_size,
                              hipStream_t stream) {
  const int* adj = (const int*)d_in[0];
  const float* feat = (const float*)d_in[1];
  const float* W = (const float*)d_in[2];
  const float* b = (const float*)d_in[3];
  float* out = (float*)d_out;

  int NC = 16;
  while (NC > 1) {
    size_t need = ((size_t)ZSZ * (2 + NC) + NN * 64) * 4 + (size_t)ZSZ * 2 * 2;
    if (need <= ws_size) break;
    NC >>= 1;
  }
  const int nsteps = NN / NC / 32;

  float* Z0 = (float*)d_ws;
  float* Z1 = Z0 + ZSZ;
  unsigned short* Zghi = (unsigned short*)(Z1 + ZSZ);
  unsigned short* Zthi = Zghi + ZSZ;
  unsigned int* mbits = (unsigned int*)(Zthi + ZSZ);
  float* part = (float*)(mbits + NN * 64);

  maskpack_kernel<<<256, 256, 0, stream>>>(adj, mbits);
  proj_kernel<<<NN, 256, 0, stream>>>(feat, W, b, Z0);

  // pack-only (Z0 already normalized)
  rp_kernel<<<512, 256, 0, stream>>>(Z0, part, 0, Z1, Zghi, Zthi);

  float* zi = Z0;
  float* zo = Z1;
  for (int it = 0; it < 4; ++it) {
    iter_kernel<<<dim3(32, NC), 256, 0, stream>>>(Zghi, Zthi, mbits, part, nsteps);
    if (it < 3) {
      rp_kernel<<<512, 256, 0, stream>>>(zi, part, NC, zo, Zghi, Zthi);
      float* tmp = zi; zi = zo; zo = tmp;
    } else {
      ro_kernel<<<NN, 256, 0, stream>>>(zi, part, NC, out);
    }
  }
}